// Round 5
// baseline (22.010 us; speedup 1.0000x reference)
//
#include <hip/hip_runtime.h>

#define NN 1024
#define DD 128

typedef float f32x4 __attribute__((ext_vector_type(4)));
typedef _Float16 f16x4 __attribute__((ext_vector_type(4)));
typedef _Float16 f16x8 __attribute__((ext_vector_type(8)));

union H2 { unsigned u; _Float16 h[2]; };

__device__ __forceinline__ f16x8 cvt8(f32x4 a, f32x4 b) {
  f16x8 r;
  r[0] = (_Float16)a.x; r[1] = (_Float16)a.y; r[2] = (_Float16)a.z; r[3] = (_Float16)a.w;
  r[4] = (_Float16)b.x; r[5] = (_Float16)b.y; r[6] = (_Float16)b.z; r[7] = (_Float16)b.w;
  return r;
}

// ws layout (f32 units):
//   [0 .. 16384)              S_part[js][i]   (16 x 1024)
//   [16384 .. 16384+2097152)  part[js][i][d]  (16 x 1024 x 128) unscaled K'@Y
#define WS_PART 16384

// Grid (16 js, 64 ib), 256 threads = 4 waves, 4 blocks/CU (launch_bounds 4/EU).
// Block tile: 16 i x 64 j. Wave w: QK^T j-subtile [w*16,+16) (swapped, lane=i),
// then K'@Y d-subtile [w*32,+32) contracting over the block's 64 j.
// Y^T lives in LDS (col-major f16, XOR-swizzled), staged once per block.
__global__ __launch_bounds__(256, 4) void gk_main(const float* __restrict__ X,
                                                  const float* __restrict__ Y,
                                                  const int* __restrict__ hp,
                                                  float* __restrict__ out,
                                                  float* __restrict__ ws) {
  __shared__ __align__(16) _Float16 Yt[128 * 64];  // [d][j] col-major, swizzled, 16KB
  __shared__ __align__(16) _Float16 Ks[16 * 64];   // [i][j] K' scaled, swizzled, 2KB
  __shared__ float yys[64];
  __shared__ unsigned msc[16];
  __shared__ float Sred[16];

  const int tid  = threadIdx.x;
  const int js   = blockIdx.x;          // 0..15  (j block of 64)
  const int ib   = blockIdx.y;          // 0..63  (i block of 16)
  const int lane = tid & 63;
  const int w    = tid >> 6;            // wave 0..3
  const int g    = lane >> 4;           // k-group 0..3
  const int li   = lane & 15;

  const float fh = (float)hp[0];
  const float inv_h2 = 1.0f / (fh * fh);

  if (tid < 16) { msc[tid] = 0u; Sred[tid] = 0.0f; }

  // ---- stage Y^T into LDS: [d][j] f16, swizzle s(d)=((d^(d>>3))&7)<<4 ----
  // unit u: j-pair jp=u>>4 (rows 2jp,2jp+1), d-oct ds8=u&15 (d = 8*ds8..+8)
  #pragma unroll
  for (int p = 0; p < 2; ++p) {
    int u  = tid + 256 * p;             // 0..511
    int jp = u >> 4, ds8 = u & 15;
    const float* ya = Y + (size_t)(js * 64 + 2 * jp) * DD + ds8 * 8;
    f32x4 a0 = *(const f32x4*)ya,        a1 = *(const f32x4*)(ya + 4);
    f32x4 b0 = *(const f32x4*)(ya + DD), b1 = *(const f32x4*)(ya + DD + 4);
    int t8 = ds8 & 7;
    #pragma unroll
    for (int c = 0; c < 8; ++c) {
      H2 pk;
      pk.h[0] = (_Float16)(c < 4 ? a0[c] : a1[c - 4]);   // Y[2jp][d]
      pk.h[1] = (_Float16)(c < 4 ? b0[c] : b1[c - 4]);   // Y[2jp+1][d]
      int d = ds8 * 8 + c;
      int byte = d * 128 + ((4 * jp) ^ ((c ^ t8) << 4));
      *(unsigned*)((char*)Yt + byte) = pk.u;
    }
  }

  // ---- X fragments + |x|^2 ----
  const float* Xr = X + (size_t)(ib * 16 + li) * DD;
  f32x4 xa[4][2];
  float xx = 0.f;
  #pragma unroll
  for (int kt = 0; kt < 4; ++kt) {
    int d0 = kt * 32 + g * 8;
    xa[kt][0] = *(const f32x4*)(Xr + d0);
    xa[kt][1] = *(const f32x4*)(Xr + d0 + 4);
    #pragma unroll
    for (int c = 0; c < 4; ++c)
      xx += xa[kt][0][c] * xa[kt][0][c] + xa[kt][1][c] * xa[kt][1][c];
  }
  xx += __shfl_xor(xx, 16); xx += __shfl_xor(xx, 32);

  // ---- Phase A: QK^T (A = Y rows j0+li, B = X rows), |y|^2 in-register ----
  const float* Yr = Y + (size_t)(js * 64 + w * 16 + li) * DD;
  f32x4 acc = {0.f, 0.f, 0.f, 0.f};
  float yy = 0.f;
  #pragma unroll
  for (int kt = 0; kt < 4; ++kt) {
    int d0 = kt * 32 + g * 8;
    f32x4 a0 = *(const f32x4*)(Yr + d0), a1 = *(const f32x4*)(Yr + d0 + 4);
    #pragma unroll
    for (int c = 0; c < 4; ++c) yy += a0[c] * a0[c] + a1[c] * a1[c];
    acc = __builtin_amdgcn_mfma_f32_16x16x32_f16(cvt8(a0, a1),
                                                 cvt8(xa[kt][0], xa[kt][1]), acc, 0, 0, 0);
  }
  yy += __shfl_xor(yy, 16); yy += __shfl_xor(yy, 32);
  if (lane < 16) yys[w * 16 + lane] = yy;
  __syncthreads();   // b1: yys + msc/Sred init + Yt staged

  // ---- exp: K = exp(inv_h2*(xy - 0.5(xx+yy))), clamped <= 1 ----
  float K[4];
  float m = 0.f, sp = 0.f;
  #pragma unroll
  for (int r = 0; r < 4; ++r) {
    int jl = w * 16 + 4 * g + r;                       // block-local j (C/D row map)
    float e = fminf((acc[r] - 0.5f * (xx + yys[jl])) * inv_h2, 0.0f);
    float kv = exp2f(e * 1.44269504088896341f);
    K[r] = kv; m = fmaxf(m, kv); sp += kv;
  }
  // K store: 16 li-rows x 4 g-quads => 16 full 64B lines per instruction
  {
    float* kb = out + (size_t)(ib * 16 + li) * NN + js * 64 + w * 16 + 4 * g;
    f32x4 k0 = { K[0], K[1], K[2], K[3] };
    *(f32x4*)kb = k0;
  }
  m = fmaxf(m, __shfl_xor(m, 16)); m = fmaxf(m, __shfl_xor(m, 32));
  sp += __shfl_xor(sp, 16);        sp += __shfl_xor(sp, 32);
  if (lane < 16) {
    atomicMax(&msc[li], __float_as_uint(m));
    atomicAdd(&Sred[li], sp);
  }
  __syncthreads();   // b2: msc, Sred complete

  // ---- scaled K' (f16) into swizzled Ks[i][j] ----
  {
    unsigned ue = (msc[li] >> 23) & 0xffu;
    unsigned se = 266u - ue; if (se > 254u) se = 254u;  // K'max in [2^12,2^13)
    float scale = __uint_as_float(se << 23);
    f16x4 q;
    #pragma unroll
    for (int r = 0; r < 4; ++r) q[r] = (_Float16)(K[r] * scale);
    int byte = li * 128 + ((32 * w + 8 * g) ^ ((li & 7) << 4));
    *(f16x4*)((char*)Ks + byte) = q;
  }
  __syncthreads();   // b3: Ks ready

  // ---- Phase D: K' @ Y. A from Ks, B from swizzled col-major Yt ----
  const int dA = w * 32 + li, dB = dA + 16;
  const int sA = ((li & 7) ^ ((dA >> 3) & 7)) << 4;
  const int sB = ((li & 7) ^ ((dB >> 3) & 7)) << 4;
  f32x4 c0 = {0.f, 0.f, 0.f, 0.f}, c1 = {0.f, 0.f, 0.f, 0.f};
  #pragma unroll
  for (int kt = 0; kt < 2; ++kt) {
    int jb = 64 * kt + 16 * g;                          // byte offset of j-chunk
    f16x8 af = *(const f16x8*)((const char*)Ks + li * 128 + (jb ^ ((li & 7) << 4)));
    f16x8 b0 = *(const f16x8*)((const char*)Yt + dA * 128 + (jb ^ sA));
    f16x8 b1 = *(const f16x8*)((const char*)Yt + dB * 128 + (jb ^ sB));
    c0 = __builtin_amdgcn_mfma_f32_16x16x32_f16(af, b0, c0, 0, 0, 0);
    c1 = __builtin_amdgcn_mfma_f32_16x16x32_f16(af, b1, c1, 0, 0, 0);
  }

  // ---- epilogue: unscale, store private partial slab ----
  float* pb = ws + WS_PART + (size_t)js * (NN * DD) + (size_t)(ib * 16) * DD;
  #pragma unroll
  for (int r = 0; r < 4; ++r) {
    int il = 4 * g + r;
    unsigned ue2 = (msc[il] >> 23) & 0xffu;
    unsigned se2 = 266u - ue2; if (se2 > 254u) se2 = 254u;
    float invs = __uint_as_float((254u - se2) << 23);   // 1/scale for row il
    pb[il * DD + dA] = c0[r] * invs;
    pb[il * DD + dB] = c1[r] * invs;
  }
  if (tid < 16) ws[js * NN + ib * 16 + tid] = Sred[tid];
}

// dK[i][d] = inv_h2 * (sum_js part[js][i][d] - (sum_js S[js][i]) * X[i][d])
__global__ __launch_bounds__(128) void dk_reduce(const float* __restrict__ X,
                                                 const int* __restrict__ hp,
                                                 const float* __restrict__ ws,
                                                 float* __restrict__ out) {
  const int unit = blockIdx.x * 128 + threadIdx.x;   // 0..32767 (f32x4 units)
  const int i  = unit >> 5;
  const int d0 = (unit & 31) * 4;
  const float fh = (float)hp[0];
  const float inv_h2 = 1.0f / (fh * fh);

  f32x4 acc = {0.f, 0.f, 0.f, 0.f};
  float s = 0.f;
  #pragma unroll
  for (int js = 0; js < 16; ++js) {
    f32x4 p = *(const f32x4*)(ws + WS_PART + (size_t)js * (NN * DD) + (size_t)i * DD + d0);
    acc.x += p.x; acc.y += p.y; acc.z += p.z; acc.w += p.w;
    s += ws[js * NN + i];
  }
  f32x4 xv = *(const f32x4*)(X + (size_t)i * DD + d0);
  f32x4 r;
  r.x = (acc.x - s * xv.x) * inv_h2;
  r.y = (acc.y - s * xv.y) * inv_h2;
  r.z = (acc.z - s * xv.z) * inv_h2;
  r.w = (acc.w - s * xv.w) * inv_h2;
  *(f32x4*)(out + (size_t)NN * NN + (size_t)i * DD + d0) = r;
}

extern "C" void kernel_launch(void* const* d_in, const int* in_sizes, int n_in,
                              void* d_out, int out_size, void* d_ws, size_t ws_size,
                              hipStream_t stream) {
  const float* X  = (const float*)d_in[0];
  const float* Y  = (const float*)d_in[1];
  const int*   hp = (const int*)d_in[2];
  float* out = (float*)d_out;
  float* ws  = (float*)d_ws;    // needs (16384 + 2097152) f32 ≈ 8.5 MB

  hipLaunchKernelGGL(gk_main, dim3(16, 64), dim3(256), 0, stream, X, Y, hp, out, ws);
  hipLaunchKernelGGL(dk_reduce, dim3(256), dim3(128), 0, stream, X, hp, ws, out);
}